// Round 11
// baseline (13751.135 us; speedup 1.0000x reference)
//
#include <hip/hip_runtime.h>
#include <cstdint>
#include <cstddef>

#define TCHUNK 64
#define NCHUNK 16
#define BATCH 32
#define IDIM 128
#define HDIM 512
#define GDIM 2048
#define ODIM 10
#define NBLK 256
#define XPSTEP (GDIM * BATCH)
#define SLAB_F 16384            // floats per t-slab: 8 groups x 4 chains x 512
#define SLAB_B (SLAB_F * 4)

typedef float f4 __attribute__((ext_vector_type(4)));
typedef float f2 __attribute__((ext_vector_type(2)));

// LLC-visible store (sc0 sc1): one-way, fire-and-forget, placement-independent
__device__ __forceinline__ void llc_store(float* p, float v) {
  asm volatile("global_store_dword %0, %1, off sc0 sc1" :: "v"(p), "v"(v) : "memory");
}
// quad (4-lane) butterfly sum via DPP quad_perm — pure VALU
__device__ __forceinline__ float quad_sum(float x) {
  int t = __builtin_amdgcn_update_dpp(0, __float_as_int(x), 0xB1, 0xF, 0xF, true);
  x += __int_as_float(t);
  t = __builtin_amdgcn_update_dpp(0, __float_as_int(x), 0x4E, 0xF, 0xF, true);
  x += __int_as_float(t);
  return x;
}

#define BARRIER() do {                                                      \
    asm volatile("s_waitcnt lgkmcnt(0)" ::: "memory");                      \
    __builtin_amdgcn_sched_barrier(0);                                      \
    __builtin_amdgcn_s_barrier();                                           \
    __builtin_amdgcn_sched_barrier(0);                                      \
  } while (0)

#define SENT_OK(v) (__float_as_uint(v.x) != 0xFFFFFFFFu && \
                    __float_as_uint(v.y) != 0xFFFFFFFFu && \
                    __float_as_uint(v.z) != 0xFFFFFFFFu && \
                    __float_as_uint(v.w) != 0xFFFFFFFFu)

// ---------------------------------------------------------------------------
// proj: P[tt][n][b] = sum_k X[tt*32+b][k] * W[n][k] + bias[n]
// ---------------------------------------------------------------------------
template<int K>
__launch_bounds__(256, 2)
__global__ void proj_kernel(const float* __restrict__ X,
                            const float* __restrict__ W,
                            const float* __restrict__ bias,
                            float* __restrict__ P) {
  __shared__ float Xs[8][132];
  __shared__ float Ws[8][132];
  const int tid = threadIdx.x;
  const int n0 = blockIdx.x * 128;
  const int m0 = blockIdx.y * 128;
  const int tx = tid & 15, ty = tid >> 4;
  const int lm = tid >> 1;
  const int kq = (tid & 1) * 4;
  f2 acc2[8][4];
#pragma unroll
  for (int i = 0; i < 8; ++i)
#pragma unroll
    for (int j = 0; j < 4; ++j) acc2[i][j] = (f2){0.f, 0.f};

  for (int k0 = 0; k0 < K; k0 += 8) {
    const float4 xv = *(const float4*)&X[(size_t)(m0 + lm) * K + k0 + kq];
    const float4 wv = *(const float4*)&W[(size_t)(n0 + lm) * K + k0 + kq];
    __syncthreads();
    Xs[kq + 0][lm] = xv.x; Xs[kq + 1][lm] = xv.y; Xs[kq + 2][lm] = xv.z; Xs[kq + 3][lm] = xv.w;
    Ws[kq + 0][lm] = wv.x; Ws[kq + 1][lm] = wv.y; Ws[kq + 2][lm] = wv.z; Ws[kq + 3][lm] = wv.w;
    __syncthreads();
#pragma unroll
    for (int kk = 0; kk < 8; ++kk) {
      float a[8];
      *(float4*)&a[0] = *(const float4*)&Xs[kk][ty * 8];
      *(float4*)&a[4] = *(const float4*)&Xs[kk][ty * 8 + 4];
      f2 b2[4];
#pragma unroll
      for (int jp = 0; jp < 4; ++jp) b2[jp] = *(const f2*)&Ws[kk][tx * 8 + 2 * jp];
#pragma unroll
      for (int i = 0; i < 8; ++i)
#pragma unroll
        for (int jp = 0; jp < 4; ++jp) acc2[i][jp] += b2[jp] * a[i];
    }
  }
  const int mb = m0 + ty * 8;
  const int t  = mb >> 5;
  const int b0 = mb & 31;
#pragma unroll
  for (int j = 0; j < 8; ++j) {
    const int n = n0 + tx * 8 + j;
    const float bj = bias[n];
    float* dst = &P[((size_t)t * GDIM + n) * BATCH + b0];
#pragma unroll
    for (int i = 0; i < 8; ++i)
      dst[i] = ((j & 1) ? acc2[i][j >> 1].y : acc2[i][j >> 1].x) + bj;
  }
}

// ---------------------------------------------------------------------------
// scan_pair: time-multiplexed dual-layer sentinel-exchange LSTM step.
// Geometry identical to the verified R10 single-layer kernel; per iteration
// each block advances layer A (chunk c+1) AND layer B (chunk c) one step,
// sharing poll (combined vmcnt), staging indices, and the 3 barriers.
// L1/L2 select active layers (single-layer prologue/epilogue launches).
// ---------------------------------------------------------------------------
template<bool L1, bool L2>
__launch_bounds__(256, 1)
__global__ void scan_pair(const float* __restrict__ xpA, const float* __restrict__ WhhA,
                          float* __restrict__ houtA, float* __restrict__ hbA,
                          float* __restrict__ ccurA, int firstA,
                          const float* __restrict__ xpB, const float* __restrict__ WhhB,
                          float* __restrict__ houtB, float* __restrict__ hbB,
                          float* __restrict__ ccurB, int firstB) {
  __shared__ float h_s1[2112];
  __shared__ float h_s2[2112];
  __shared__ float red1[1024];
  __shared__ float red2[1024];
  __shared__ float gate1[256];
  __shared__ float gate2[256];
  __shared__ float pad[13952];      // total LDS = 82944B > 80KB -> 1 block/CU

  const int tid = threadIdx.x, bid = blockIdx.x;
  const int g = bid & 7, rank = bid >> 3, slot16 = rank * 16;
  const int w = tid >> 6, l = tid & 63;
  const int s4 = l & 3, rq = l >> 2;
  const int sg = 4 * w + s4;
  const int cx = sg & 7;
  const int kb = 32 * sg;

  // ---- W slices into VGPRs, column-permuted (as R10) ----
  float wregA[4][32], wregB[4][32];
  if constexpr (L1) {
#pragma unroll
    for (int r = 0; r < 4; ++r) {
      const int rl = 4 * rq + r;
      const float* wp = WhhA + (size_t)((rl >> 4) * HDIM + slot16 + (rl & 15)) * HDIM + kb;
#pragma unroll
      for (int e = 0; e < 32; ++e) wregA[r][e] = wp[e ^ cx];
    }
  }
  if constexpr (L2) {
#pragma unroll
    for (int r = 0; r < 4; ++r) {
      const int rl = 4 * rq + r;
      const float* wp = WhhB + (size_t)((rl >> 4) * HDIM + slot16 + (rl & 15)) * HDIM + kb;
#pragma unroll
      for (int e = 0; e < 32; ++e) wregB[r][e] = wp[e ^ cx];
    }
  }

  // staging role (t-invariant) — verbatim R10
  const int cl = l >> 4, m = l & 15;
  const int sgS = 4 * w + (m >> 2);
  const int sig = sgS & 7;
  int dsaddr[8];
#pragma unroll
  for (int i = 0; i < 8; ++i)
    dsaddr[i] = 132 * sgS + 4 * (8 * (m & 3) + (i ^ sig)) + cl;
  const int srcoff = cl * 512 + 128 * w + 8 * m;

  // gate-cell role
  const int qg = tid >> 6, jg = (tid >> 2) & 15, bg = tid & 3;
  const size_t xqo = (size_t)(qg * HDIM + slot16 + jg) * BATCH + g * 4 + bg;

  // update role (wave 0)
  const int jj = l >> 2, bb = l & 3;
  const size_t cco = (size_t)(g * 4 + bb) * HDIM + slot16 + jj;

  float cA = 0.f, cB = 0.f;
  if (w == 0) {
    if (L1 && !firstA) cA = ccurA[cco];
    if (L2 && !firstB) cB = ccurB[cco];
  }

  const float* hp1 = &h_s1[132 * sg];
  const float* hp2 = &h_s2[132 * sg];

#pragma unroll 1
  for (int tt = 0; tt < TCHUNK; ++tt) {
    // ---- combined poll + stage h(tt) for active layers ----
    const float* s1 = hbA + (size_t)tt * SLAB_F + g * 2048 + srcoff;
    const float* s2 = hbB + (size_t)tt * SLAB_F + g * 2048 + srcoff;
    f4 va1, vb1, va2, vb2;
    int guard = 0;
    while (true) {
      bool ok;
      if constexpr (L1 && L2) {
        asm volatile("global_load_dwordx4 %0, %4, off sc0 sc1\n\t"
                     "global_load_dwordx4 %1, %5, off sc0 sc1\n\t"
                     "global_load_dwordx4 %2, %6, off sc0 sc1\n\t"
                     "global_load_dwordx4 %3, %7, off sc0 sc1\n\t"
                     "s_waitcnt vmcnt(0)"
                     : "=&v"(va1), "=&v"(vb1), "=&v"(va2), "=&v"(vb2)
                     : "v"(s1), "v"(s1 + 4), "v"(s2), "v"(s2 + 4) : "memory");
        ok = SENT_OK(va1) && SENT_OK(vb1) && SENT_OK(va2) && SENT_OK(vb2);
      } else if constexpr (L1) {
        asm volatile("global_load_dwordx4 %0, %2, off sc0 sc1\n\t"
                     "global_load_dwordx4 %1, %3, off sc0 sc1\n\t"
                     "s_waitcnt vmcnt(0)"
                     : "=&v"(va1), "=&v"(vb1) : "v"(s1), "v"(s1 + 4) : "memory");
        ok = SENT_OK(va1) && SENT_OK(vb1);
      } else {
        asm volatile("global_load_dwordx4 %0, %2, off sc0 sc1\n\t"
                     "global_load_dwordx4 %1, %3, off sc0 sc1\n\t"
                     "s_waitcnt vmcnt(0)"
                     : "=&v"(va2), "=&v"(vb2) : "v"(s2), "v"(s2 + 4) : "memory");
        ok = SENT_OK(va2) && SENT_OK(vb2);
      }
      if (__all(ok) || ++guard > 200000) break;
      __builtin_amdgcn_s_sleep(1);
    }
    if constexpr (L1) {
      h_s1[dsaddr[0]] = va1.x; h_s1[dsaddr[1]] = va1.y;
      h_s1[dsaddr[2]] = va1.z; h_s1[dsaddr[3]] = va1.w;
      h_s1[dsaddr[4]] = vb1.x; h_s1[dsaddr[5]] = vb1.y;
      h_s1[dsaddr[6]] = vb1.z; h_s1[dsaddr[7]] = vb1.w;
    }
    if constexpr (L2) {
      h_s2[dsaddr[0]] = va2.x; h_s2[dsaddr[1]] = va2.y;
      h_s2[dsaddr[2]] = va2.z; h_s2[dsaddr[3]] = va2.w;
      h_s2[dsaddr[4]] = vb2.x; h_s2[dsaddr[5]] = vb2.y;
      h_s2[dsaddr[6]] = vb2.z; h_s2[dsaddr[7]] = vb2.w;
    }
    float xpv1 = 0.f, xpv2 = 0.f;
    if constexpr (L1) xpv1 = xpA[(size_t)tt * XPSTEP + xqo];
    if constexpr (L2) xpv2 = xpB[(size_t)tt * XPSTEP + xqo];
    BARRIER();                                  // h_s(tt) ready

#define DOT_PHASE(HPTR, WREG, RED)                                          \
    {                                                                       \
      f2 a01[4], a23[4];                                                    \
      _Pragma("unroll")                                                     \
      for (int r = 0; r < 4; ++r) { a01[r] = (f2){0.f,0.f}; a23[r] = (f2){0.f,0.f}; } \
      _Pragma("unroll")                                                     \
      for (int kk = 0; kk < 32; ++kk) {                                     \
        const f4 hv = *(const f4*)&HPTR[4 * kk];                            \
        const f2 h01 = {hv.x, hv.y}, h23 = {hv.z, hv.w};                    \
        _Pragma("unroll")                                                   \
        for (int r = 0; r < 4; ++r) {                                       \
          a01[r] += h01 * WREG[r][kk];                                      \
          a23[r] += h23 * WREG[r][kk];                                      \
        }                                                                   \
      }                                                                     \
      _Pragma("unroll")                                                     \
      for (int r = 0; r < 4; ++r) {                                         \
        a01[r].x = quad_sum(a01[r].x); a01[r].y = quad_sum(a01[r].y);       \
        a23[r].x = quad_sum(a23[r].x); a23[r].y = quad_sum(a23[r].y);       \
      }                                                                     \
      f2 r01, r23;                                                          \
      { const f2 v0 = (s4 & 1) ? a01[1] : a01[0];                           \
        const f2 v1 = (s4 & 1) ? a01[3] : a01[2];                           \
        r01 = (s4 & 2) ? v1 : v0;                                           \
        const f2 u0 = (s4 & 1) ? a23[1] : a23[0];                           \
        const f2 u1 = (s4 & 1) ? a23[3] : a23[2];                           \
        r23 = (s4 & 2) ? u1 : u0; }                                         \
      *(f4*)&RED[(w << 8) + 4 * l] = (f4){r01.x, r01.y, r23.x, r23.y};      \
    }

    if constexpr (L1) DOT_PHASE(hp1, wregA, red1)
    if constexpr (L2) DOT_PHASE(hp2, wregB, red2)
    BARRIER();                                  // red(tt) ready

    if constexpr (L1) {
      const float pre = red1[tid] + red1[256 + tid] + red1[512 + tid] + red1[768 + tid] + xpv1;
      gate1[tid] = (qg == 2) ? tanhf(pre) : 1.f / (1.f + __expf(-pre));
    }
    if constexpr (L2) {
      const float pre = red2[tid] + red2[256 + tid] + red2[512 + tid] + red2[768 + tid] + xpv2;
      gate2[tid] = (qg == 2) ? tanhf(pre) : 1.f / (1.f + __expf(-pre));
    }
    BARRIER();                                  // gates ready

    if (w == 0) {
      if constexpr (L1) {
        const float ig = gate1[jj * 4 + bb];
        const float fg = gate1[64 + jj * 4 + bb];
        const float gg = gate1[128 + jj * 4 + bb];
        const float og = gate1[192 + jj * 4 + bb];
        cA = fg * cA + ig * gg;
        const float hval = og * tanhf(cA);
        llc_store(hbA + (size_t)(tt + 1) * SLAB_F + g * 2048 + bb * 512 + slot16 + jj, hval);
        houtA[(size_t)tt * (BATCH * HDIM) + cco] = hval;
      }
      if constexpr (L2) {
        const float ig = gate2[jj * 4 + bb];
        const float fg = gate2[64 + jj * 4 + bb];
        const float gg = gate2[128 + jj * 4 + bb];
        const float og = gate2[192 + jj * 4 + bb];
        cB = fg * cB + ig * gg;
        const float hval = og * tanhf(cB);
        llc_store(hbB + (size_t)(tt + 1) * SLAB_F + g * 2048 + bb * 512 + slot16 + jj, hval);
        houtB[(size_t)tt * (BATCH * HDIM) + cco] = hval;
      }
    }
#undef DOT_PHASE
  }
  if (w == 0) {
    if constexpr (L1) ccurA[cco] = cA;
    if constexpr (L2) ccurB[cco] = cB;
  }
  ((volatile float*)pad)[tid] = cA + cB;        // keep LDS pad allocated
}

// ---------------------------------------------------------------------------
// head: logits = h2 @ W3^T + b3 ; softmax over 10. One wave per row.
// ---------------------------------------------------------------------------
__launch_bounds__(256, 2)
__global__ void head_kernel(const float* __restrict__ h2,
                            const float* __restrict__ W3,
                            const float* __restrict__ b3,
                            float* __restrict__ outp) {
  const int tid = threadIdx.x;
  const int lane = tid & 63;
  const int wv = tid >> 6;
  const int row = blockIdx.x * 4 + wv;
  const float* hrow = &h2[(size_t)row * HDIM];
  float hreg[8];
  *(float4*)&hreg[0] = *(const float4*)&hrow[lane * 8];
  *(float4*)&hreg[4] = *(const float4*)&hrow[lane * 8 + 4];
  float logit[ODIM];
#pragma unroll
  for (int o = 0; o < ODIM; ++o) {
    const float* wrow = &W3[o * HDIM + lane * 8];
    float w[8];
    *(float4*)&w[0] = *(const float4*)&wrow[0];
    *(float4*)&w[4] = *(const float4*)&wrow[4];
    float pp = 0.f;
#pragma unroll
    for (int j = 0; j < 8; ++j) pp += hreg[j] * w[j];
#pragma unroll
    for (int off = 32; off > 0; off >>= 1) pp += __shfl_xor(pp, off);
    logit[o] = pp + b3[o];
  }
  float mx = logit[0];
#pragma unroll
  for (int o = 1; o < ODIM; ++o) mx = fmaxf(mx, logit[o]);
  float ssum = 0.f;
#pragma unroll
  for (int o = 0; o < ODIM; ++o) { logit[o] = __expf(logit[o] - mx); ssum += logit[o]; }
  const float inv = 1.f / ssum;
  if (lane == 0) {
    float* dst = &outp[(size_t)row * ODIM];
#pragma unroll
    for (int o = 0; o < ODIM; ++o) dst[o] = logit[o] * inv;
  }
}

// ---------------------------------------------------------------------------
extern "C" void kernel_launch(void* const* d_in, const int* in_sizes, int n_in,
                              void* d_out, int out_size, void* d_ws, size_t ws_size,
                              hipStream_t stream) {
  const float* data  = (const float*)d_in[0];
  const float* W_ih1 = (const float*)d_in[1];
  const float* W_hh1 = (const float*)d_in[2];
  const float* b1    = (const float*)d_in[3];
  const float* W_ih2 = (const float*)d_in[4];
  const float* W_hh2 = (const float*)d_in[5];
  const float* b2    = (const float*)d_in[6];
  const float* W3    = (const float*)d_in[7];
  const float* b3    = (const float*)d_in[8];
  float* outp = (float*)d_out;

  char* ws = (char*)d_ws;
  size_t off = 0;
  float* xp1   = (float*)(ws + off); off += (size_t)TCHUNK * GDIM * BATCH * 4;     // 16MB
  float* xp2   = (float*)(ws + off); off += (size_t)TCHUNK * GDIM * BATCH * 4;     // 16MB
  float* h1c   = (float*)(ws + off); off += (size_t)TCHUNK * BATCH * HDIM * 4;     // 4MB
  float* h2c   = (float*)(ws + off); off += (size_t)TCHUNK * BATCH * HDIM * 4;     // 4MB
  float* hb1   = (float*)(ws + off); off += (size_t)(TCHUNK + 1) * SLAB_B;         // 4.25MB
  float* hb2   = (float*)(ws + off); off += (size_t)(TCHUNK + 1) * SLAB_B;
  float* ccur1 = (float*)(ws + off); off += BATCH * HDIM * 4;
  float* ccur2 = (float*)(ws + off); off += BATCH * HDIM * 4;
  if (off > ws_size) return;   // ws too small: bail visibly

  // slab 0 = h(0) = zeros; slabs 1..TCHUNK = sentinel 0xFFFFFFFF
  hipMemsetAsync(hb1, 0x00, SLAB_B, stream);
  hipMemsetAsync((char*)hb1 + SLAB_B, 0xFF, (size_t)TCHUNK * SLAB_B, stream);
  hipMemsetAsync(hb2, 0x00, SLAB_B, stream);
  hipMemsetAsync((char*)hb2 + SLAB_B, 0xFF, (size_t)TCHUNK * SLAB_B, stream);

  const dim3 pgrid(GDIM / 128, (TCHUNK * BATCH) / 128);

#define RECYCLE(HB) do {                                                    \
    hipMemcpyAsync(HB, (char*)HB + (size_t)TCHUNK * SLAB_B, SLAB_B,         \
                   hipMemcpyDeviceToDevice, stream);                        \
    hipMemsetAsync((char*)HB + SLAB_B, 0xFF, (size_t)TCHUNK * SLAB_B, stream); \
  } while (0)

  // prologue: layer-1 chunk 0 alone
  proj_kernel<IDIM><<<pgrid, 256, 0, stream>>>(data, W_ih1, b1, xp1);
  scan_pair<true, false><<<NBLK, 256, 0, stream>>>(
      xp1, W_hh1, h1c, hb1, ccur1, 1, xp2, W_hh2, h2c, hb2, ccur2, 1);
  RECYCLE(hb1);
  proj_kernel<HDIM><<<pgrid, 256, 0, stream>>>(h1c, W_ih2, b2, xp2);   // chunk 0
  proj_kernel<IDIM><<<pgrid, 256, 0, stream>>>(
      data + (size_t)TCHUNK * BATCH * IDIM, W_ih1, b1, xp1);           // chunk 1

  for (int c = 0; c < NCHUNK - 1; ++c) {
    // pair: layer-1 chunk c+1  ||  layer-2 chunk c
    scan_pair<true, true><<<NBLK, 256, 0, stream>>>(
        xp1, W_hh1, h1c, hb1, ccur1, 0,
        xp2, W_hh2, h2c, hb2, ccur2, c == 0);
    head_kernel<<<(TCHUNK * BATCH) / 4, 256, 0, stream>>>(
        h2c, W3, b3, outp + (size_t)c * TCHUNK * BATCH * ODIM);
    RECYCLE(hb1);
    RECYCLE(hb2);
    proj_kernel<HDIM><<<pgrid, 256, 0, stream>>>(h1c, W_ih2, b2, xp2); // chunk c+1
    if (c + 2 < NCHUNK)
      proj_kernel<IDIM><<<pgrid, 256, 0, stream>>>(
          data + (size_t)(c + 2) * TCHUNK * BATCH * IDIM, W_ih1, b1, xp1);
  }

  // epilogue: layer-2 chunk 15 alone
  scan_pair<false, true><<<NBLK, 256, 0, stream>>>(
      xp1, W_hh1, h1c, hb1, ccur1, 0, xp2, W_hh2, h2c, hb2, ccur2, 0);
  head_kernel<<<(TCHUNK * BATCH) / 4, 256, 0, stream>>>(
      h2c, W3, b3, outp + (size_t)(NCHUNK - 1) * TCHUNK * BATCH * ODIM);
#undef RECYCLE
}